// Round 18
// baseline (27.009 us; speedup 1.0000x reference)
//
#include <hip/hip_runtime.h>
#include <math.h>

#define NQ     9
#define NDIM   256
#define NHID   130
#define NST    512
#define NBATCH 64
#define MCAP   460

typedef float f2 __attribute__((ext_vector_type(2)));
typedef unsigned uint2v __attribute__((ext_vector_type(2)));

__device__ __forceinline__ float softplusf(float x) {
    return (x > 0.f) ? (x + log1pf(expf(-x))) : log1pf(expf(x));
}

// DPP-based XOR lane swaps (VALU pipe):
template<int CTRL>
__device__ __forceinline__ float dpp_f(float v) {
    int i = __float_as_int(v);
    return __int_as_float(__builtin_amdgcn_update_dpp(i, i, CTRL, 0xF, 0xF, false));
}
__device__ __forceinline__ float swzx16(float v) {   // DS fallback lane^16
    return __int_as_float(__builtin_amdgcn_ds_swizzle(__float_as_int(v), 0x401F));
}
__device__ __forceinline__ float bperm(int addr, float v) {  // DS fallback lane^32
    return __int_as_float(__builtin_amdgcn_ds_bpermute(addr, __float_as_int(v)));
}
__device__ __forceinline__ float lx16(float v, bool hi) {
#if __has_builtin(__builtin_amdgcn_permlane16_swap)
    uint2v r = __builtin_amdgcn_permlane16_swap(__float_as_uint(v), __float_as_uint(v), false, false);
    return __uint_as_float(hi ? r[0] : r[1]);
#else
    return swzx16(v);
#endif
}
__device__ __forceinline__ float lx32(float v, bool hi, int bpaddr) {
#if __has_builtin(__builtin_amdgcn_permlane32_swap)
    uint2v r = __builtin_amdgcn_permlane32_swap(__float_as_uint(v), __float_as_uint(v), false, false);
    return __uint_as_float(hi ? r[0] : r[1]);
#else
    return bperm(bpaddr, v);
#endif
}

// packed helpers: apply 32-bit lane-swap to both halves
template<int CTRL>
__device__ __forceinline__ f2 dpp2(f2 v) {
    f2 r; r.x = dpp_f<CTRL>(v.x); r.y = dpp_f<CTRL>(v.y); return r;
}
__device__ __forceinline__ f2 lx16_2(f2 v, bool hi) {
    f2 r; r.x = lx16(v.x, hi); r.y = lx16(v.y, hi); return r;
}
__device__ __forceinline__ f2 lx32_2(f2 v, bool hi, int a) {
    f2 r; r.x = lx32(v.x, hi, a); r.y = lx32(v.y, hi, a); return r;
}
#define PKFMA(A, B, C) __builtin_elementwise_fma(A, B, C)

// Packed Chebyshev step: NP = (2*xhat)*CP - NP.  Pair i = states (i, i|4);
// pair-element bit = qubit 6; pair-index bits = qubits 7,8; lane bits = 0..5.
#define MVP(NP, CP)                                                           \
  do {                                                                        \
    _Pragma("unroll")                                                         \
    for (int i = 0; i < 4; ++i) {                                             \
      const f2 a = CP[i];                                                     \
      f2 y = dgp[i] * a;                                                      \
      y = PKFMA(in2v0, CP[i^1], y);                                           \
      y = PKFMA(in2v1, CP[i^2], y);                                           \
      y = PKFMA(in2v2, __builtin_shufflevector(a, a, 1, 0), y);               \
      y = PKFMA(cx2v[0], dpp2<0xB1>(a), y);                                   \
      y = PKFMA(cx2v[1], dpp2<0x4E>(a), y);                                   \
      const f2 a7 = dpp2<0x141>(a);                                           \
      y = PKFMA(cx2v[2], dpp2<0x1B>(a7), y);                                  \
      y = PKFMA(cx2v[3], dpp2<0x140>(a7), y);                                 \
      y = PKFMA(cx2v[4], lx16_2(a, h16), y);                                  \
      y = PKFMA(cx2v[5], lx32_2(a, h32, bpaddr), y);                          \
      NP[i] = y - NP[i];                                                      \
    }                                                                         \
  } while (0)

#define COEFP(P, K)                                                           \
  do { const float ck = 2.0f * jlf[K];                                        \
    switch ((K) & 3) {                                                        \
      case 0: _Pragma("unroll") for (int i=0;i<4;++i) accr[i] += ck*P[i]; break; \
      case 1: _Pragma("unroll") for (int i=0;i<4;++i) acci[i] -= ck*P[i]; break; \
      case 2: _Pragma("unroll") for (int i=0;i<4;++i) accr[i] -= ck*P[i]; break; \
      case 3: _Pragma("unroll") for (int i=0;i<4;++i) acci[i] += ck*P[i]; break; \
    }                                                                         \
  } while (0)

// FUSED: one block per batch, 256 threads. Stage W1->LDS float4; MLP;
// evolution on wave 0 (lockstep, barrier-free), gauge-transformed REAL
// Chebyshev with packed-FP32 (v_pk_fma_f32) matvec.
__global__ __launch_bounds__(256) void fused_kernel(
    const float* __restrict__ x,    const float* __restrict__ mask,
    const float* __restrict__ adj,  const float* __restrict__ W1,
    const float* __restrict__ b1,   const float* __restrict__ W2,
    const float* __restrict__ b2,   float* __restrict__ out)
{
    const int b    = blockIdx.x;
    const int tid  = threadIdx.x;
    const int w    = tid >> 6;
    const int lane = tid & 63;

    __shared__ __align__(16) float w1s[NDIM * NHID];   // 133 KB; aliased later
    __shared__ float xs[NDIM];
    __shared__ float hs[NHID + 2];
    __shared__ float vs[4];
    __shared__ float ms[NQ];
    __shared__ float adjs[81];
    __shared__ float Wm[81];
    __shared__ double Ssh;

    // ---- stage: W1 (float4), x, mask, adj ----
    {
        const float4* W14 = (const float4*)W1;
        float4* d4 = (float4*)w1s;
        #pragma unroll 4
        for (int i = tid; i < (NDIM*NHID)/4; i += 256) d4[i] = W14[i];
        if (tid < NDIM/4) ((float4*)xs)[tid] = ((const float4*)(x + b*NDIM))[tid];
        if (tid >= 64 && tid < 64 + NQ) ms[tid - 64] = mask[b*NQ + (tid - 64)];
        if (tid >= 128 && tid < 128 + 81) adjs[tid - 128] = adj[tid - 128];
    }
    __syncthreads();

    // ---- layer 1 ----
    if (tid < NHID) {
        float a0 = b1[tid], a1 = 0.f;
        #pragma unroll 8
        for (int i = 0; i < NDIM; i += 2) {
            a0 = fmaf(xs[i],     w1s[i*NHID + tid],       a0);
            a1 = fmaf(xs[i + 1], w1s[(i + 1)*NHID + tid], a1);
        }
        hs[tid] = fmaxf(a0 + a1, 0.f);
    }
    __syncthreads();

    // ---- layer 2 ----
    {
        float p = hs[lane]      * W2[lane*4 + w]
                + hs[lane + 64] * W2[(lane + 64)*4 + w];
        if (lane < 2) p += hs[128 + lane] * W2[(128 + lane)*4 + w];
        #pragma unroll
        for (int off = 32; off; off >>= 1) p += __shfl_down(p, off);
        if (lane == 0) vs[w] = p + b2[w];
    }
    __syncthreads();

    if (w != 0) return;   // wave 0 evolves, lockstep, barrier-free

    double* fd  = (double*)w1s;          // alias dead W1 region
    float*  jlf = w1s + 2*(MCAP + 8);

    for (int e = lane; e < 81; e += 64) {
        int i = e / 9, j = e % 9;
        Wm[e] = (866.0f/729.0f) * adjs[e] * ms[i] * ms[j];
    }

    const float omega = softplusf(vs[0]);
    const float delta = vs[1];
    const float phi   = vs[2];
    const float t     = softplusf(vs[3]);
    const float halfw = 0.5f * omega;

    // ---- diagonal via occupancy factorization ----
    float oL[6];
    #pragma unroll
    for (int i = 0; i < 6; ++i) oL[i] = ((lane >> (5 - i)) & 1) ? 0.f : 1.f;
    float t1 = 0.f, moL = 0.f;
    for (int i = 0; i < 6; ++i) {
        moL = fmaf(ms[i], oL[i], moL);
        float row = 0.f;
        for (int j = 0; j < 6; ++j) row = fmaf(Wm[i*9 + j], oL[j], row);
        t1 = fmaf(oL[i], row, t1);
    }
    float g[3];
    for (int p = 0; p < 3; ++p) {
        float gp = 0.f;
        for (int i = 0; i < 6; ++i) gp = fmaf(Wm[i*9 + 6 + p], oL[i], gp);
        g[p] = gp;
    }
    const float w67 = Wm[6*9 + 7], w68 = Wm[6*9 + 8], w78 = Wm[7*9 + 8];
    float Dd[8];
    #pragma unroll
    for (int r = 0; r < 8; ++r) {
        const float o0 = (r & 4) ? 0.f : 1.f;
        const float o1 = (r & 2) ? 0.f : 1.f;
        const float o2 = (r & 1) ? 0.f : 1.f;
        const float cross = g[0]*o0 + g[1]*o1 + g[2]*o2;
        const float rr    = w67*o0*o1 + w68*o0*o2 + w78*o1*o2;
        const float mo_r  = moL + ms[6]*o0 + ms[7]*o1 + ms[8]*o2;
        Dd[r] = t1 + 2.f*(cross + rr) - delta*mo_r;
    }

    // ---- spectral interval ----
    float mx = Dd[0], mn = Dd[0];
    #pragma unroll
    for (int r = 1; r < 8; ++r) { mx = fmaxf(mx, Dd[r]); mn = fminf(mn, Dd[r]); }
    #pragma unroll
    for (int off = 1; off < 64; off <<= 1) {
        mx = fmaxf(mx, __shfl_xor(mx, off));
        mn = fminf(mn, __shfl_xor(mn, off));
    }
    float sm = 0.f;
    for (int j = 0; j < NQ; ++j) sm += ms[j];
    const float c0   = 0.5f * (mx + mn);
    const float rho  = (0.5f * (mx - mn) + halfw * sm) * 1.003f;
    const float rhoE = fmaxf(rho, 1e-20f);
    const float zc   = t * rho;

    int M;
    const bool tiny = (zc < 0.5f);
    if (tiny) M = 8;
    else {
        M = (int)ceilf(zc + 3.5f * cbrtf(zc + 4.f) + 4.f);
        if (M > MCAP) M = MCAP;
    }

    // ---- Bessel table (lockstep) ----
    if (tiny) {
        if (lane <= 8) {
            const float zh = 0.5f * zc;
            const float q  = zh * zh;
            float fact = 1.f;
            for (int i = 2; i <= lane; ++i) fact *= (float)i;
            const float pw = (lane == 0) ? 1.f : powf(zh, (float)lane);
            jlf[lane] = (pw / fact) *
                (1.f - q/(float)(lane+1) + 0.5f*q*q/(float)((lane+1)*(lane+2)));
        }
    } else {
        if (lane == 0) {
            const double zz  = (double)zc;
            const double inv = 1.0 / zz;
            const int   M2   = M + 20 + M/10;
            double fkp1 = 0.0, fk = 1e-30;
            for (int k = M2; k >= 1; --k) {
                double fkm1 = 2.0 * (double)k * inv * fk - fkp1;
                fkp1 = fk; fk = fkm1;
                const int idx = k - 1;
                if (idx <= M) fd[idx] = fk;
            }
            double S = fd[0];
            for (int idx = 2; idx <= M; idx += 2) S += 2.0 * fd[idx];
            Ssh = S;
        }
        for (int k = lane; k <= M; k += 64) jlf[k] = (float)(fd[k] / Ssh);
    }

    // ---- packed coefficients of 2*xhat ----
    const float two_rho = 2.0f / rhoE;
    f2 dgp[4];
    #pragma unroll
    for (int i = 0; i < 4; ++i) {
        dgp[i].x = (Dd[i]     - c0) * two_rho;
        dgp[i].y = (Dd[i + 4] - c0) * two_rho;
    }
    f2 cx2v[6];
    #pragma unroll
    for (int q = 0; q < 6; ++q) {
        const float c = ms[5 - q] * halfw * two_rho;
        cx2v[q].x = c; cx2v[q].y = c;
    }
    // in-lane couplings: in2v0 ~ qubit8 (r^1), in2v1 ~ qubit7 (r^2), in2v2 ~ qubit6 (r^4)
    f2 in2v0, in2v1, in2v2;
    { const float c = ms[8] * halfw * two_rho; in2v0.x = c; in2v0.y = c; }
    { const float c = ms[7] * halfw * two_rho; in2v1.x = c; in2v1.y = c; }
    { const float c = ms[6] * halfw * two_rho; in2v2.x = c; in2v2.y = c; }
    const int  bpaddr = (lane ^ 32) << 2;
    const bool h16    = (lane & 16) != 0;
    const bool h32    = (lane & 32) != 0;

    // ---- packed Chebyshev recurrence ----
    f2 p0[4], p1[4], accr[4], acci[4];
    #pragma unroll
    for (int i = 0; i < 4; ++i) {
        p0[i] = (f2){0.f, 0.f}; p1[i] = (f2){0.f, 0.f};
        acci[i] = (f2){0.f, 0.f};
    }
    p0[0].x = (lane == 0) ? 1.f : 0.f;

    const float J0 = jlf[0];
    #pragma unroll
    for (int i = 0; i < 4; ++i) accr[i] = J0 * p0[i];

    MVP(p1, p0);
    #pragma unroll
    for (int i = 0; i < 4; ++i) p1[i] = p1[i] * 0.5f;
    { const float c1 = 2.0f * jlf[1];
      #pragma unroll
      for (int i = 0; i < 4; ++i) acci[i] -= c1 * p1[i]; }

    int k = 2;
    while (k <= M) {
        MVP(p0, p1);
        COEFP(p0, k);
        ++k;
        if (k > M) break;
        MVP(p1, p0);
        COEFP(p1, k);
        ++k;
    }

    // ---- undo gauge + shift; packed float4 stores ----
    const float base = t * c0;
    const float pcl  = (float)__popc(lane);
    float o[8];
    #pragma unroll
    for (int i = 0; i < 4; ++i) {
        const float pc_i = pcl + (float)__popc(i);
        {   // r = i (element 0)
            float sb, cb;
            __sincosf(base + phi * pc_i, &sb, &cb);
            o[i] = accr[i].x*cb + acci[i].x*sb;
        }
        {   // r = i+4 (element 1, one extra set bit)
            float sb, cb;
            __sincosf(base + phi * (pc_i + 1.f), &sb, &cb);
            o[i + 4] = accr[i].y*cb + acci[i].y*sb;
        }
    }
    float4* o4 = (float4*)(out + b*NST + (lane << 3));
    o4[0] = make_float4(o[0], o[1], o[2], o[3]);
    o4[1] = make_float4(o[4], o[5], o[6], o[7]);
}

extern "C" void kernel_launch(void* const* d_in, const int* in_sizes, int n_in,
                              void* d_out, int out_size, void* d_ws, size_t ws_size,
                              hipStream_t stream) {
    // Size-keyed input routing (pairwise-distinct element counts):
    //   x:16384  mask:576  adj:81  W1:33280  b1:130  W2:520  b2:4
    const float *x = nullptr, *msk = nullptr, *adj = nullptr,
                *W1 = nullptr, *b1 = nullptr, *W2 = nullptr, *b2 = nullptr;
    for (int i = 0; i < n_in; ++i) {
        const float* p = (const float*)d_in[i];
        switch (in_sizes[i]) {
            case 16384: x   = p; break;
            case 576:   msk = p; break;
            case 81:    adj = p; break;
            case 33280: W1  = p; break;
            case 130:   b1  = p; break;
            case 520:   W2  = p; break;
            case 4:     b2  = p; break;
            default: break;
        }
    }
    fused_kernel<<<NBATCH, 256, 0, stream>>>(x, msk, adj, W1, b1, W2, b2,
                                             (float*)d_out);
}

// Round 19
// 26.720 us; speedup vs baseline: 1.0108x; 1.0108x over previous
//
#include <hip/hip_runtime.h>
#include <math.h>

#define NQ     9
#define NDIM   256
#define NHID   130
#define NST    512
#define NBATCH 64
#define MCAP   460

typedef unsigned uint2v __attribute__((ext_vector_type(2)));

__device__ __forceinline__ float softplusf(float x) {
    return (x > 0.f) ? (x + log1pf(expf(-x))) : log1pf(expf(x));
}

// DPP-based XOR lane swaps (VALU pipe):
template<int CTRL>
__device__ __forceinline__ float dpp_f(float v) {
    int i = __float_as_int(v);
    return __int_as_float(__builtin_amdgcn_update_dpp(i, i, CTRL, 0xF, 0xF, false));
}
__device__ __forceinline__ float swzx16(float v) {
    return __int_as_float(__builtin_amdgcn_ds_swizzle(__float_as_int(v), 0x401F));
}
__device__ __forceinline__ float bperm(int addr, float v) {
    return __int_as_float(__builtin_amdgcn_ds_bpermute(addr, __float_as_int(v)));
}
__device__ __forceinline__ float lx16(float v, bool hi) {
#if __has_builtin(__builtin_amdgcn_permlane16_swap)
    uint2v r = __builtin_amdgcn_permlane16_swap(__float_as_uint(v), __float_as_uint(v), false, false);
    return __uint_as_float(hi ? r[0] : r[1]);
#else
    return swzx16(v);
#endif
}
__device__ __forceinline__ float lx32(float v, bool hi, int bpaddr) {
#if __has_builtin(__builtin_amdgcn_permlane32_swap)
    uint2v r = __builtin_amdgcn_permlane32_swap(__float_as_uint(v), __float_as_uint(v), false, false);
    return __uint_as_float(hi ? r[0] : r[1]);
#else
    return bperm(bpaddr, v);
#endif
}

// async global->LDS 16B (no VGPR round-trip); lds base must be wave-uniform.
__device__ __forceinline__ void gl_lds16(const float4* g, float4* l) {
#if __has_builtin(__builtin_amdgcn_global_load_lds)
    __builtin_amdgcn_global_load_lds(
        (const __attribute__((address_space(1))) void*)g,
        (__attribute__((address_space(3))) void*)l, 16, 0, 0);
#else
    *l = *g;
#endif
}

// Chebyshev step on REAL vectors: NR = (2*xhat)*CR - NR   (scalar, all-VALU)
#define MV(NR, CR)                                                            \
  do {                                                                        \
    _Pragma("unroll")                                                         \
    for (int r = 0; r < 8; ++r) {                                             \
      const float a = CR[r];                                                  \
      float yr = dg2[r] * a;                                                  \
      yr = fmaf(in2[0], CR[r^1], yr);                                         \
      yr = fmaf(in2[1], CR[r^2], yr);                                         \
      yr = fmaf(in2[2], CR[r^4], yr);                                         \
      yr = fmaf(cx2[0], dpp_f<0xB1>(a), yr);                                  \
      yr = fmaf(cx2[1], dpp_f<0x4E>(a), yr);                                  \
      const float a7 = dpp_f<0x141>(a);                                       \
      yr = fmaf(cx2[2], dpp_f<0x1B>(a7), yr);                                 \
      yr = fmaf(cx2[3], dpp_f<0x140>(a7), yr);                                \
      yr = fmaf(cx2[4], lx16(a, h16), yr);                                    \
      yr = fmaf(cx2[5], lx32(a, h32, bpaddr), yr);                            \
      NR[r] = yr - NR[r];                                                     \
    }                                                                         \
  } while (0)

// FUSED, fetch-optimized. One block/batch, 256 threads. W1+x staged via
// global_load_lds (all loads in flight, one drain). Evolution on wave 0
// (lockstep): REAL Chebyshev, SINGLE MV expansion (ping-pong + reg swap).
__global__ __launch_bounds__(256) void fused_kernel(
    const float* __restrict__ x,    const float* __restrict__ mask,
    const float* __restrict__ adj,  const float* __restrict__ W1,
    const float* __restrict__ b1,   const float* __restrict__ W2,
    const float* __restrict__ b2,   float* __restrict__ out)
{
    const int b    = blockIdx.x;
    const int tid  = threadIdx.x;
    const int w    = tid >> 6;
    const int lane = tid & 63;

    __shared__ __align__(16) float w1s[NDIM * NHID];   // 133 KB; aliased later
    __shared__ __align__(16) float xs[NDIM];
    __shared__ float hs[NHID + 2];
    __shared__ float vs[4];
    __shared__ float ms[NQ];
    __shared__ float adjs[81];
    __shared__ float Wm[81];
    __shared__ double Ssh;

    // ---- stage: W1 + x via global_load_lds; mask/adj scalar ----
    {
        const float4* W14 = (const float4*)W1;
        float4* d4 = (float4*)w1s;
        const int wb = tid & ~63;                    // wave-uniform
        for (int it = 0; it < 32; ++it)
            gl_lds16(W14 + it*256 + tid, d4 + it*256 + wb);
        if (tid < 128)
            gl_lds16(W14 + 8192 + tid, d4 + 8192 + wb);
        if (tid < 64)
            gl_lds16((const float4*)(x + b*NDIM) + tid, (float4*)xs);
        if (tid >= 64 && tid < 64 + NQ) ms[tid - 64] = mask[b*NQ + (tid - 64)];
        if (tid >= 128 && tid < 128 + 81) adjs[tid - 128] = adj[tid - 128];
    }
    __syncthreads();

    // ---- layer 1 ----
    if (tid < NHID) {
        float a0 = b1[tid], a1 = 0.f;
        #pragma unroll 8
        for (int i = 0; i < NDIM; i += 2) {
            a0 = fmaf(xs[i],     w1s[i*NHID + tid],       a0);
            a1 = fmaf(xs[i + 1], w1s[(i + 1)*NHID + tid], a1);
        }
        hs[tid] = fmaxf(a0 + a1, 0.f);
    }
    __syncthreads();

    // ---- layer 2 ----
    {
        float p = hs[lane]      * W2[lane*4 + w]
                + hs[lane + 64] * W2[(lane + 64)*4 + w];
        if (lane < 2) p += hs[128 + lane] * W2[(128 + lane)*4 + w];
        #pragma unroll
        for (int off = 32; off; off >>= 1) p += __shfl_down(p, off);
        if (lane == 0) vs[w] = p + b2[w];
    }
    __syncthreads();

    if (w != 0) return;   // wave 0 evolves, lockstep, barrier-free

    double* fd  = (double*)w1s;          // alias dead W1 region
    float*  jlf = w1s + 2*(MCAP + 8);

    for (int e = lane; e < 81; e += 64) {
        int i = e / 9, j = e % 9;
        Wm[e] = (866.0f/729.0f) * adjs[e] * ms[i] * ms[j];
    }

    const float omega = softplusf(vs[0]);
    const float delta = vs[1];
    const float phi   = vs[2];
    const float t     = softplusf(vs[3]);
    const float halfw = 0.5f * omega;

    // ---- diagonal via occupancy factorization ----
    float oL[6];
    #pragma unroll
    for (int i = 0; i < 6; ++i) oL[i] = ((lane >> (5 - i)) & 1) ? 0.f : 1.f;
    float t1 = 0.f, moL = 0.f;
    for (int i = 0; i < 6; ++i) {
        moL = fmaf(ms[i], oL[i], moL);
        float row = 0.f;
        for (int j = 0; j < 6; ++j) row = fmaf(Wm[i*9 + j], oL[j], row);
        t1 = fmaf(oL[i], row, t1);
    }
    float g[3];
    for (int p = 0; p < 3; ++p) {
        float gp = 0.f;
        for (int i = 0; i < 6; ++i) gp = fmaf(Wm[i*9 + 6 + p], oL[i], gp);
        g[p] = gp;
    }
    const float w67 = Wm[6*9 + 7], w68 = Wm[6*9 + 8], w78 = Wm[7*9 + 8];
    float Dd[8];
    #pragma unroll
    for (int r = 0; r < 8; ++r) {
        const float o0 = (r & 4) ? 0.f : 1.f;
        const float o1 = (r & 2) ? 0.f : 1.f;
        const float o2 = (r & 1) ? 0.f : 1.f;
        const float cross = g[0]*o0 + g[1]*o1 + g[2]*o2;
        const float rr    = w67*o0*o1 + w68*o0*o2 + w78*o1*o2;
        const float mo_r  = moL + ms[6]*o0 + ms[7]*o1 + ms[8]*o2;
        Dd[r] = t1 + 2.f*(cross + rr) - delta*mo_r;
    }

    // ---- spectral interval ----
    float mx = Dd[0], mn = Dd[0];
    #pragma unroll
    for (int r = 1; r < 8; ++r) { mx = fmaxf(mx, Dd[r]); mn = fminf(mn, Dd[r]); }
    #pragma unroll
    for (int off = 1; off < 64; off <<= 1) {
        mx = fmaxf(mx, __shfl_xor(mx, off));
        mn = fminf(mn, __shfl_xor(mn, off));
    }
    float sm = 0.f;
    for (int j = 0; j < NQ; ++j) sm += ms[j];
    const float c0   = 0.5f * (mx + mn);
    const float rho  = (0.5f * (mx - mn) + halfw * sm) * 1.003f;
    const float rhoE = fmaxf(rho, 1e-20f);
    const float zc   = t * rho;

    int M;
    const bool tiny = (zc < 0.5f);
    if (tiny) M = 8;
    else {
        M = (int)ceilf(zc + 3.2f * cbrtf(zc + 4.f) + 3.5f);
        if (M > MCAP) M = MCAP;
    }

    // ---- Bessel table (lockstep; no powf) ----
    if (tiny) {
        if (lane <= 8) {
            const float zh = 0.5f * zc;
            const float q  = zh * zh;
            float fact = 1.f, pw = 1.f;
            for (int i = 2; i <= lane; ++i) fact *= (float)i;
            for (int i = 0; i < lane; ++i) pw *= zh;
            jlf[lane] = (pw / fact) *
                (1.f - q/(float)(lane+1) + 0.5f*q*q/(float)((lane+1)*(lane+2)));
        }
    } else {
        if (lane == 0) {
            const double zz  = (double)zc;
            const double inv = 1.0 / zz;
            const int   M2   = M + 20 + M/10;
            double fkp1 = 0.0, fk = 1e-30;
            for (int k = M2; k >= 1; --k) {
                double fkm1 = 2.0 * (double)k * inv * fk - fkp1;
                fkp1 = fk; fk = fkm1;
                const int idx = k - 1;
                if (idx <= M) fd[idx] = fk;
            }
            double S = fd[0];
            for (int idx = 2; idx <= M; idx += 2) S += 2.0 * fd[idx];
            Ssh = S;
        }
        for (int k = lane; k <= M; k += 64) jlf[k] = (float)(fd[k] / Ssh);
    }

    // ---- folded REAL coefficients of 2*xhat ----
    const float two_rho = 2.0f / rhoE;
    float dg2[8];
    #pragma unroll
    for (int r = 0; r < 8; ++r) dg2[r] = (Dd[r] - c0) * two_rho;
    float cx2[6];
    #pragma unroll
    for (int q = 0; q < 6; ++q) cx2[q] = ms[5 - q] * halfw * two_rho;
    float in2[3];
    #pragma unroll
    for (int p = 0; p < 3; ++p) in2[p] = ms[8 - p] * halfw * two_rho;
    const int  bpaddr = (lane ^ 32) << 2;
    const bool h16    = (lane & 16) != 0;
    const bool h32    = (lane & 32) != 0;

    // ---- Chebyshev recurrence: A=T_{k-2}, B=T_{k-1}; single MV expansion ----
    float A[8], B[8], accr[8], acci[8];
    #pragma unroll
    for (int r = 0; r < 8; ++r) { A[r] = 0.f; B[r] = 0.f; acci[r] = 0.f; accr[r] = 0.f; }
    A[0] = (lane == 0) ? 1.f : 0.f;                  // T0 = e0
    // T1 = xhat*e0 in closed form (sparse column 0):
    if (lane == 0) {
        B[0] = 0.5f * dg2[0];
        B[1] = 0.5f * in2[0];   // qubit 8 (r^1)
        B[2] = 0.5f * in2[1];   // qubit 7 (r^2)
        B[4] = 0.5f * in2[2];   // qubit 6 (r^4)
    } else if (lane == 1 || lane == 2 || lane == 4 || lane == 8 || lane == 16 || lane == 32) {
        const int q = 31 - __clz(lane);
        B[0] = 0.5f * cx2[q];
    }
    accr[0] = jlf[0] * A[0];
    { const float c1 = 2.0f * jlf[1];
      #pragma unroll
      for (int r = 0; r < 8; ++r) acci[r] -= c1 * B[r]; }

    int k = 2;
    #pragma clang loop unroll(disable)
    while (k <= M) {
        MV(A, B);                    // A = 2*xhat*B - A = T_k
        { const float ck = 2.0f * jlf[k];
          switch (k & 3) {
            case 0: { _Pragma("unroll") for (int r=0;r<8;++r) accr[r] += ck*A[r]; } break;
            case 1: { _Pragma("unroll") for (int r=0;r<8;++r) acci[r] -= ck*A[r]; } break;
            case 2: { _Pragma("unroll") for (int r=0;r<8;++r) accr[r] -= ck*A[r]; } break;
            case 3: { _Pragma("unroll") for (int r=0;r<8;++r) acci[r] += ck*A[r]; } break;
          }
        }
        #pragma unroll
        for (int r = 0; r < 8; ++r) { const float tp = A[r]; A[r] = B[r]; B[r] = tp; }
        ++k;
    }

    // ---- undo gauge+shift: 2 sincos + 4 precomputed phases ----
    const float pcl = (float)__popc(lane);
    float C[4], S[4];
    {
        float s0, c0b, su, cu;
        __sincosf(t * c0 + phi * pcl, &s0, &c0b);    // beta at popc(r)=0
        __sincosf(phi, &su, &cu);                     // increment
        C[0] = c0b; S[0] = s0;
        #pragma clang loop unroll(disable)
        for (int n = 1; n < 4; ++n) {                 // beta += phi
            C[n] = C[n-1]*cu - S[n-1]*su;
            S[n] = S[n-1]*cu + C[n-1]*su;             // NOTE uses updated C? no:
        }
    }
    // fix the rotation (use temporaries to avoid the aliasing above)
    {
        float c = C[0], s = S[0], su, cu;
        __sincosf(phi, &su, &cu);
        #pragma unroll
        for (int n = 1; n < 4; ++n) {
            const float cn = c*cu - s*su;
            const float sn = s*cu + c*su;
            C[n] = cn; S[n] = sn; c = cn; s = sn;
        }
    }
    float o[8];
    #pragma unroll
    for (int r = 0; r < 8; ++r) {
        const int n = __popc(r);
        o[r] = accr[r]*C[n] + acci[r]*S[n];
    }
    float4* o4 = (float4*)(out + b*NST + (lane << 3));
    o4[0] = make_float4(o[0], o[1], o[2], o[3]);
    o4[1] = make_float4(o[4], o[5], o[6], o[7]);
}

extern "C" void kernel_launch(void* const* d_in, const int* in_sizes, int n_in,
                              void* d_out, int out_size, void* d_ws, size_t ws_size,
                              hipStream_t stream) {
    // Size-keyed input routing (pairwise-distinct element counts):
    //   x:16384  mask:576  adj:81  W1:33280  b1:130  W2:520  b2:4
    const float *x = nullptr, *msk = nullptr, *adj = nullptr,
                *W1 = nullptr, *b1 = nullptr, *W2 = nullptr, *b2 = nullptr;
    for (int i = 0; i < n_in; ++i) {
        const float* p = (const float*)d_in[i];
        switch (in_sizes[i]) {
            case 16384: x   = p; break;
            case 576:   msk = p; break;
            case 81:    adj = p; break;
            case 33280: W1  = p; break;
            case 130:   b1  = p; break;
            case 520:   W2  = p; break;
            case 4:     b2  = p; break;
            default: break;
        }
    }
    fused_kernel<<<NBATCH, 256, 0, stream>>>(x, msk, adj, W1, b1, W2, b2,
                                             (float*)d_out);
}

// Round 20
// 24.849 us; speedup vs baseline: 1.0869x; 1.0753x over previous
//
#include <hip/hip_runtime.h>
#include <math.h>

#define NQ     9
#define NDIM   256
#define NHID   130
#define NST    512
#define NBATCH 64
#define MCAP   460

typedef unsigned uint2v __attribute__((ext_vector_type(2)));

__device__ __forceinline__ float softplusf(float x) {
    return (x > 0.f) ? (x + log1pf(expf(-x))) : log1pf(expf(x));
}

// DPP-based XOR lane swaps (VALU pipe):
template<int CTRL>
__device__ __forceinline__ float dpp_f(float v) {
    int i = __float_as_int(v);
    return __int_as_float(__builtin_amdgcn_update_dpp(i, i, CTRL, 0xF, 0xF, false));
}
__device__ __forceinline__ float swzx16(float v) {
    return __int_as_float(__builtin_amdgcn_ds_swizzle(__float_as_int(v), 0x401F));
}
__device__ __forceinline__ float bperm(int addr, float v) {
    return __int_as_float(__builtin_amdgcn_ds_bpermute(addr, __float_as_int(v)));
}
__device__ __forceinline__ float lx16(float v, bool hi) {
#if __has_builtin(__builtin_amdgcn_permlane16_swap)
    uint2v r = __builtin_amdgcn_permlane16_swap(__float_as_uint(v), __float_as_uint(v), false, false);
    return __uint_as_float(hi ? r[0] : r[1]);
#else
    return swzx16(v);
#endif
}
__device__ __forceinline__ float lx32(float v, bool hi, int bpaddr) {
#if __has_builtin(__builtin_amdgcn_permlane32_swap)
    uint2v r = __builtin_amdgcn_permlane32_swap(__float_as_uint(v), __float_as_uint(v), false, false);
    return __uint_as_float(hi ? r[0] : r[1]);
#else
    return bperm(bpaddr, v);
#endif
}

// Chebyshev step on REAL vectors: NR = (2*xhat)*CR - NR   (all-VALU)
#define MV(NR, CR)                                                            \
  do {                                                                        \
    _Pragma("unroll")                                                         \
    for (int r = 0; r < 8; ++r) {                                             \
      const float a = CR[r];                                                  \
      float yr = dg2[r] * a;                                                  \
      yr = fmaf(in2[0], CR[r^1], yr);                                         \
      yr = fmaf(in2[1], CR[r^2], yr);                                         \
      yr = fmaf(in2[2], CR[r^4], yr);                                         \
      yr = fmaf(cx2[0], dpp_f<0xB1>(a), yr);                                  \
      yr = fmaf(cx2[1], dpp_f<0x4E>(a), yr);                                  \
      const float a7 = dpp_f<0x141>(a);                                       \
      yr = fmaf(cx2[2], dpp_f<0x1B>(a7), yr);                                 \
      yr = fmaf(cx2[3], dpp_f<0x140>(a7), yr);                                \
      yr = fmaf(cx2[4], lx16(a, h16), yr);                                    \
      yr = fmaf(cx2[5], lx32(a, h32, bpaddr), yr);                            \
      NR[r] = yr - NR[r];                                                     \
    }                                                                         \
  } while (0)

#define COEF(P, K)                                                            \
  do { const float ck = 2.0f * jlf[K];                                        \
    switch ((K) & 3) {                                                        \
      case 0: _Pragma("unroll") for (int r=0;r<8;++r) accr[r] += ck*P[r]; break; \
      case 1: _Pragma("unroll") for (int r=0;r<8;++r) acci[r] -= ck*P[r]; break; \
      case 2: _Pragma("unroll") for (int r=0;r<8;++r) accr[r] -= ck*P[r]; break; \
      case 3: _Pragma("unroll") for (int r=0;r<8;++r) acci[r] += ck*P[r]; break; \
    }                                                                         \
  } while (0)

// FUSED (R17 structure + micro-trims). One block per batch, 256 threads.
// Stage W1->LDS float4; MLP (layer1 130thr dual-acc, layer2 warp-reduce);
// evolution on wave 0 (lockstep, barrier-free): rolled-diag factorization,
// REAL Chebyshev with DPP/permlane cross-lane, no-powf Bessel, 2-sincos
// phase-rotation epilogue.
__global__ __launch_bounds__(256) void fused_kernel(
    const float* __restrict__ x,    const float* __restrict__ mask,
    const float* __restrict__ adj,  const float* __restrict__ W1,
    const float* __restrict__ b1,   const float* __restrict__ W2,
    const float* __restrict__ b2,   float* __restrict__ out)
{
    const int b    = blockIdx.x;
    const int tid  = threadIdx.x;
    const int w    = tid >> 6;
    const int lane = tid & 63;

    __shared__ __align__(16) float w1s[NDIM * NHID];   // 133 KB; aliased later
    __shared__ float xs[NDIM];
    __shared__ float hs[NHID + 2];
    __shared__ float vs[4];
    __shared__ float ms[NQ];
    __shared__ float adjs[81];
    __shared__ float Wm[81];
    __shared__ double Ssh;

    // ---- stage: W1 (all threads, float4), x, mask, adj ----
    {
        const float4* W14 = (const float4*)W1;
        float4* d4 = (float4*)w1s;
        #pragma unroll 4
        for (int i = tid; i < (NDIM*NHID)/4; i += 256) d4[i] = W14[i];
        if (tid < NDIM/4) ((float4*)xs)[tid] = ((const float4*)(x + b*NDIM))[tid];
        if (tid >= 64 && tid < 64 + NQ) ms[tid - 64] = mask[b*NQ + (tid - 64)];
        if (tid >= 128 && tid < 128 + 81) adjs[tid - 128] = adj[tid - 128];
    }
    __syncthreads();

    // ---- layer 1: hidden = relu(x @ W1 + b1), dual accumulators ----
    if (tid < NHID) {
        float a0 = b1[tid], a1 = 0.f;
        #pragma unroll 8
        for (int i = 0; i < NDIM; i += 2) {
            a0 = fmaf(xs[i],     w1s[i*NHID + tid],       a0);
            a1 = fmaf(xs[i + 1], w1s[(i + 1)*NHID + tid], a1);
        }
        hs[tid] = fmaxf(a0 + a1, 0.f);
    }
    __syncthreads();

    // ---- layer 2: warp w computes v[w] via wave reduction ----
    {
        float p = hs[lane]      * W2[lane*4 + w]
                + hs[lane + 64] * W2[(lane + 64)*4 + w];
        if (lane < 2) p += hs[128 + lane] * W2[(128 + lane)*4 + w];
        #pragma unroll
        for (int off = 32; off; off >>= 1) p += __shfl_down(p, off);
        if (lane == 0) vs[w] = p + b2[w];
    }
    __syncthreads();

    if (w != 0) return;   // wave 0 evolves, lockstep, barrier-free

    // Bessel tables alias the dead W1 staging region.
    double* fd  = (double*)w1s;
    float*  jlf = w1s + 2*(MCAP + 8);

    // ---- weighted adjacency (rolled) ----
    for (int e = lane; e < 81; e += 64) {
        int i = e / 9, j = e % 9;
        Wm[e] = (866.0f/729.0f) * adjs[e] * ms[i] * ms[j];
    }

    const float omega = softplusf(vs[0]);
    const float delta = vs[1];
    const float phi   = vs[2];
    const float t     = softplusf(vs[3]);
    const float halfw = 0.5f * omega;

    // ---- diagonal via occupancy factorization ----
    float oL[6];
    #pragma unroll
    for (int i = 0; i < 6; ++i) oL[i] = ((lane >> (5 - i)) & 1) ? 0.f : 1.f;
    float t1 = 0.f, moL = 0.f;
    for (int i = 0; i < 6; ++i) {
        moL = fmaf(ms[i], oL[i], moL);
        float row = 0.f;
        for (int j = 0; j < 6; ++j) row = fmaf(Wm[i*9 + j], oL[j], row);
        t1 = fmaf(oL[i], row, t1);
    }
    float g[3];
    for (int p = 0; p < 3; ++p) {
        float gp = 0.f;
        for (int i = 0; i < 6; ++i) gp = fmaf(Wm[i*9 + 6 + p], oL[i], gp);
        g[p] = gp;
    }
    const float w67 = Wm[6*9 + 7], w68 = Wm[6*9 + 8], w78 = Wm[7*9 + 8];
    float Dd[8];
    #pragma unroll
    for (int r = 0; r < 8; ++r) {
        const float o0 = (r & 4) ? 0.f : 1.f;
        const float o1 = (r & 2) ? 0.f : 1.f;
        const float o2 = (r & 1) ? 0.f : 1.f;
        const float cross = g[0]*o0 + g[1]*o1 + g[2]*o2;
        const float rr    = w67*o0*o1 + w68*o0*o2 + w78*o1*o2;
        const float mo_r  = moL + ms[6]*o0 + ms[7]*o1 + ms[8]*o2;
        Dd[r] = t1 + 2.f*(cross + rr) - delta*mo_r;
    }

    // ---- spectral interval ----
    float mx = Dd[0], mn = Dd[0];
    #pragma unroll
    for (int r = 1; r < 8; ++r) { mx = fmaxf(mx, Dd[r]); mn = fminf(mn, Dd[r]); }
    #pragma unroll
    for (int off = 1; off < 64; off <<= 1) {
        mx = fmaxf(mx, __shfl_xor(mx, off));
        mn = fminf(mn, __shfl_xor(mn, off));
    }
    float sm = 0.f;
    for (int j = 0; j < NQ; ++j) sm += ms[j];
    const float c0   = 0.5f * (mx + mn);
    const float rho  = (0.5f * (mx - mn) + halfw * sm) * 1.003f;
    const float rhoE = fmaxf(rho, 1e-20f);
    const float zc   = t * rho;

    int M;
    const bool tiny = (zc < 0.5f);
    if (tiny) M = 8;
    else {
        M = (int)ceilf(zc + 3.2f * cbrtf(zc + 4.f) + 3.5f);
        if (M > MCAP) M = MCAP;
    }

    // ---- Bessel table J_0..J_M (lockstep; no powf) ----
    if (tiny) {
        if (lane <= 8) {
            const float zh = 0.5f * zc;
            const float q  = zh * zh;
            float fact = 1.f, pw = 1.f;
            for (int i = 2; i <= lane; ++i) fact *= (float)i;
            for (int i = 0; i < lane; ++i) pw *= zh;
            jlf[lane] = (pw / fact) *
                (1.f - q/(float)(lane+1) + 0.5f*q*q/(float)((lane+1)*(lane+2)));
        }
    } else {
        if (lane == 0) {
            const double zz  = (double)zc;
            const double inv = 1.0 / zz;
            const int   M2   = M + 20 + M/10;
            double fkp1 = 0.0, fk = 1e-30;
            for (int k = M2; k >= 1; --k) {
                double fkm1 = 2.0 * (double)k * inv * fk - fkp1;
                fkp1 = fk; fk = fkm1;
                const int idx = k - 1;
                if (idx <= M) fd[idx] = fk;
            }
            double S = fd[0];
            for (int idx = 2; idx <= M; idx += 2) S += 2.0 * fd[idx];
            Ssh = S;
        }
        for (int k = lane; k <= M; k += 64) jlf[k] = (float)(fd[k] / Ssh);
    }

    // ---- folded REAL coefficients of 2*xhat ----
    const float two_rho = 2.0f / rhoE;
    float dg2[8];
    #pragma unroll
    for (int r = 0; r < 8; ++r) dg2[r] = (Dd[r] - c0) * two_rho;
    float cx2[6];
    #pragma unroll
    for (int q = 0; q < 6; ++q) cx2[q] = ms[5 - q] * halfw * two_rho;
    float in2[3];
    #pragma unroll
    for (int p = 0; p < 3; ++p) in2[p] = ms[8 - p] * halfw * two_rho;
    const int  bpaddr = (lane ^ 32) << 2;
    const bool h16    = (lane & 16) != 0;
    const bool h32    = (lane & 32) != 0;

    // ---- Chebyshev recurrence (REAL vectors; R17 two-MV loop body) ----
    float p0[8], p1[8], accr[8], acci[8];
    #pragma unroll
    for (int r = 0; r < 8; ++r) { p0[r] = 0.f; p1[r] = 0.f; acci[r] = 0.f; }
    p0[0] = (lane == 0) ? 1.f : 0.f;

    const float J0 = jlf[0];
    #pragma unroll
    for (int r = 0; r < 8; ++r) accr[r] = J0 * p0[r];

    MV(p1, p0);                       // p1 = 2*xhat*p0 (p1 was 0); halve
    #pragma unroll
    for (int r = 0; r < 8; ++r) p1[r] *= 0.5f;
    { const float c1 = 2.0f * jlf[1];
      #pragma unroll
      for (int r = 0; r < 8; ++r) acci[r] -= c1 * p1[r]; }

    int k = 2;
    while (k <= M) {
        MV(p0, p1);                   // p0 = 2*xhat*p1 - p0
        COEF(p0, k);
        ++k;
        if (k > M) break;
        MV(p1, p0);                   // p1 = 2*xhat*p0 - p1
        COEF(p1, k);
        ++k;
    }

    // ---- undo gauge + shift: 2 sincos + phase rotation; float4 stores ----
    const float pcl = (float)__popc(lane);
    float C[4], S[4];
    {
        float s0, cb0, su, cu;
        __sincosf(t * c0 + phi * pcl, &s0, &cb0);   // beta at popc(r)=0
        __sincosf(phi, &su, &cu);                    // per-bit increment
        C[0] = cb0; S[0] = s0;
        float c = cb0, s = s0;
        #pragma unroll
        for (int n = 1; n < 4; ++n) {
            const float cn = c*cu - s*su;
            const float sn = s*cu + c*su;
            C[n] = cn; S[n] = sn; c = cn; s = sn;
        }
    }
    float o[8];
    #pragma unroll
    for (int r = 0; r < 8; ++r) {
        const int n = __popc(r);
        o[r] = accr[r]*C[n] + acci[r]*S[n];
    }
    float4* o4 = (float4*)(out + b*NST + (lane << 3));
    o4[0] = make_float4(o[0], o[1], o[2], o[3]);
    o4[1] = make_float4(o[4], o[5], o[6], o[7]);
}

extern "C" void kernel_launch(void* const* d_in, const int* in_sizes, int n_in,
                              void* d_out, int out_size, void* d_ws, size_t ws_size,
                              hipStream_t stream) {
    // Size-keyed input routing (pairwise-distinct element counts):
    //   x:16384  mask:576  adj:81  W1:33280  b1:130  W2:520  b2:4
    const float *x = nullptr, *msk = nullptr, *adj = nullptr,
                *W1 = nullptr, *b1 = nullptr, *W2 = nullptr, *b2 = nullptr;
    for (int i = 0; i < n_in; ++i) {
        const float* p = (const float*)d_in[i];
        switch (in_sizes[i]) {
            case 16384: x   = p; break;
            case 576:   msk = p; break;
            case 81:    adj = p; break;
            case 33280: W1  = p; break;
            case 130:   b1  = p; break;
            case 520:   W2  = p; break;
            case 4:     b2  = p; break;
            default: break;
        }
    }
    fused_kernel<<<NBATCH, 256, 0, stream>>>(x, msk, adj, W1, b1, W2, b2,
                                             (float*)d_out);
}